// Round 10
// baseline (169.511 us; speedup 1.0000x reference)
//
#include <hip/hip_runtime.h>

// SAdapter v10: two single-purpose streaming kernels through d_ws.
// K1 (read-stream): per-image A (token GEMM) -> BC (z_star->P) -> C2 (z_hist)
//     writes ZH flat (1568 f32/image) to ws + class-token passthrough.
// K2 (write-stream): per-image y = z_hist @ hist_w^T + hist_b.
//     ZH staged in LDS, hist_w row in regs, coalesced b32 stores.
// Lessons kept: no min-wave launch bounds, no per-thread arrays >8 floats
// (v5/v7 spill disasters), correct flat-reshape semantics (v3 lesson).

#define DIMD 192
#define IMGS 37824            // 197*192

// ---------------- K1: head (A -> BC -> C2) ----------------
__launch_bounds__(256)
__global__ void k1_head(
    const float* __restrict__ x,
    const float* __restrict__ W1,
    const float* __restrict__ b1,
    const float* __restrict__ conv1_w,
    const float* __restrict__ conv1_b,
    const float* __restrict__ cdc_w,
    const float* __restrict__ wc1,
    const float* __restrict__ wc2,
    float* __restrict__ zh_ws,
    float* __restrict__ out)
{
    __shared__ float smem[4608];   // 18432 B
    float* TS  = smem;             // [8][16][16] padded t (border 0)
    float* PS  = smem + 2048;      // [8][16][16] padded P (border 1)
    float* WB2 = smem + 4096;      // [64][8] packed small weights

    const int tid = threadIdx.x;
    const float* xb   = x   + (size_t)blockIdx.x * IMGS;
    float*       outb = out + (size_t)blockIdx.x * IMGS;

    // ---- Phase 0: init borders, pack weights ----
    {
        float4 z4 = make_float4(0.f, 0.f, 0.f, 0.f);
        float4 o4 = make_float4(1.f, 1.f, 1.f, 1.f);
        ((float4*)TS)[tid]       = z4;
        ((float4*)TS)[tid + 256] = z4;
        ((float4*)PS)[tid]       = o4;
        ((float4*)PS)[tid + 256] = o4;
    }
    if (tid < 64) {
        const float* c5 = cdc_w + tid * 5;                 // cdc_w (8,8,1,5), tid=o*8+i
        float k0 = c5[0], k1 = c5[1], k2 = c5[2], k3 = c5[3], k4 = c5[4];
        float kd = k0 + k1 + k2 + k3 + k4;
        float* wp = WB2 + tid * 8;
        wp[0] = conv1_w[tid] + k2 - 0.7f * kd;  // center: 1x1 + cdc-center - theta*diff
        wp[1] = k0; wp[2] = k1; wp[3] = k3; wp[4] = k4;    // up,left,right,down
        wp[5] = wc1[tid];
        wp[6] = wc2[tid];
        wp[7] = 0.f;
    }
    __syncthreads();

    // ---- Phase A: t[n,c] = tok[n,:] @ W1[c,:] + b1[c] (per-token row GEMM) ----
    if (tid < 196) {
        const float4* rowp = (const float4*)(xb + DIMD + tid * DIMD);
        float acc[8];
        #pragma unroll
        for (int c = 0; c < 8; ++c) acc[c] = b1[c];        // uniform -> s_load
        #pragma unroll
        for (int blk = 0; blk < 6; ++blk) {                // 6 batches of 32 d
            float4 tv[8];
            #pragma unroll
            for (int u = 0; u < 8; ++u) tv[u] = rowp[blk * 8 + u];
            #pragma unroll
            for (int c = 0; c < 8; ++c) {
                const float* wrow = W1 + c * DIMD + blk * 32;  // contiguous, uniform
                #pragma unroll
                for (int u = 0; u < 8; ++u) {
                    acc[c] += tv[u].x * wrow[u * 4 + 0] + tv[u].y * wrow[u * 4 + 1]
                            + tv[u].z * wrow[u * 4 + 2] + tv[u].w * wrow[u * 4 + 3];
                }
            }
        }
        int h = tid / 14, w = tid - h * 14;
        float* tp = TS + (h + 1) * 16 + (w + 1);
        #pragma unroll
        for (int c = 0; c < 8; ++c) tp[c * 256] = acc[c];
    } else if (tid >= 208) {
        ((float4*)outb)[tid - 208] = ((const float4*)xb)[tid - 208];  // class token
    }
    __syncthreads();

    // ---- Phase BC: z_star in regs -> mu/gamma -> P = exp(-(g*(z-mu))^2) ----
    if (tid < 196) {
        int h = tid / 14, w = tid - h * 14;
        const float* tp = TS + (h + 1) * 16 + (w + 1);
        float zv[8];
        #pragma unroll
        for (int c = 0; c < 8; ++c) zv[c] = conv1_b[c];    // uniform -> s_load
        #pragma unroll
        for (int i = 0; i < 8; ++i) {
            float t0 = tp[i * 256];
            float tu = tp[i * 256 - 16];
            float td = tp[i * 256 + 16];
            float tl = tp[i * 256 - 1];
            float tr = tp[i * 256 + 1];
            #pragma unroll
            for (int c = 0; c < 8; ++c) {
                const float* wp = WB2 + (c * 8 + i) * 8;   // broadcast b128 + b32
                float4 wv = *(const float4*)wp;
                float wd = wp[4];
                zv[c] += wv.x * t0 + wv.y * tu + wv.z * tl + wv.w * tr + wd * td;
            }
        }
        float* pp = PS + (h + 1) * 16 + (w + 1);
        #pragma unroll
        for (int c = 0; c < 8; ++c) {
            float mu = 0.f, ga = 0.f;
            #pragma unroll
            for (int i = 0; i < 8; ++i) {
                const float* wp = WB2 + (c * 8 + i) * 8;
                mu += wp[5] * zv[i];
                ga += wp[6] * zv[i];
            }
            float e = ga * (zv[c] - mu);
            pp[c * 256] = __expf(-e * e);
        }
    }
    __syncthreads();

    // ---- Phase C2: z_hist = 3x3 box / 9, flat (c*196+hw), straight to ws ----
    if (tid < 196) {
        int h = tid / 14, w = tid - h * 14;
        const float* pb = PS + h * 16 + w;    // top-left of 3x3 window (padded coords)
        float* zg = zh_ws + (size_t)blockIdx.x * 1568;
        #pragma unroll
        for (int c = 0; c < 8; ++c) {
            const float* pr = pb + c * 256;
            float s9 = pr[0]  + pr[1]  + pr[2]
                     + pr[16] + pr[17] + pr[18]
                     + pr[32] + pr[33] + pr[34];
            zg[c * 196 + tid] = s9 * (1.f / 9.f);   // coalesced per c
        }
    }
}

// ---------------- K2: hist GEMM (write stream) ----------------
__launch_bounds__(192)
__global__ void k2_hist(
    const float* __restrict__ zh_ws,
    const float* __restrict__ hist_w,
    const float* __restrict__ hist_b,
    float* __restrict__ out)
{
    __shared__ float zsh[1568];
    const int d = threadIdx.x;            // output dim 0..191
    const float* zg = zh_ws + (size_t)blockIdx.x * 1568;

    // stage ZH (6272 B) into LDS, coalesced
    for (int f = d; f < 392; f += 192)
        ((float4*)zsh)[f] = ((const float4*)zg)[f];

    const float4 h0 = *(const float4*)(hist_w + d * 8);      // hist_w (192,8) row
    const float4 h1 = *(const float4*)(hist_w + d * 8 + 4);
    const float  hb = hist_b[d];
    __syncthreads();

    float* oy = out + (size_t)blockIdx.x * IMGS + DIMD;
    #pragma unroll 4
    for (int n2 = 0; n2 < 196; ++n2) {
        const float4 z0 = *(const float4*)(zsh + n2 * 8);    // broadcast b128
        const float4 z1 = *(const float4*)(zsh + n2 * 8 + 4);
        oy[n2 * DIMD + d] = hb
            + z0.x * h0.x + z0.y * h0.y + z0.z * h0.z + z0.w * h0.w
            + z1.x * h1.x + z1.y * h1.y + z1.z * h1.z + z1.w * h1.w;
    }
}

// ---------------- fused fallback (v9, only if ws too small) ----------------
__launch_bounds__(256)
__global__ void sadapter_fused(
    const float* __restrict__ x,
    const float* __restrict__ W1,
    const float* __restrict__ b1,
    const float* __restrict__ conv1_w,
    const float* __restrict__ conv1_b,
    const float* __restrict__ cdc_w,
    const float* __restrict__ wc1,
    const float* __restrict__ wc2,
    const float* __restrict__ hist_w,
    const float* __restrict__ hist_b,
    float* __restrict__ out)
{
    __shared__ float smem[4608];
    float* TS  = smem;
    float* ZH  = smem;
    float* PS  = smem + 2048;
    float* WB2 = smem + 4096;
    const int tid = threadIdx.x;
    const float* xb   = x   + (size_t)blockIdx.x * IMGS;
    float*       outb = out + (size_t)blockIdx.x * IMGS;

    {
        float4 z4 = make_float4(0.f,0.f,0.f,0.f), o4 = make_float4(1.f,1.f,1.f,1.f);
        ((float4*)TS)[tid] = z4; ((float4*)TS)[tid+256] = z4;
        ((float4*)PS)[tid] = o4; ((float4*)PS)[tid+256] = o4;
    }
    if (tid < 64) {
        const float* c5 = cdc_w + tid * 5;
        float k0=c5[0],k1=c5[1],k2=c5[2],k3=c5[3],k4=c5[4];
        float kd = k0+k1+k2+k3+k4;
        float* wp = WB2 + tid*8;
        wp[0]=conv1_w[tid]+k2-0.7f*kd; wp[1]=k0; wp[2]=k1; wp[3]=k3; wp[4]=k4;
        wp[5]=wc1[tid]; wp[6]=wc2[tid]; wp[7]=0.f;
    }
    __syncthreads();
    if (tid < 196) {
        const float4* rowp = (const float4*)(xb + DIMD + tid * DIMD);
        float acc[8];
        #pragma unroll
        for (int c=0;c<8;++c) acc[c]=b1[c];
        #pragma unroll
        for (int blk=0; blk<6; ++blk) {
            float4 tv[8];
            #pragma unroll
            for (int u=0;u<8;++u) tv[u]=rowp[blk*8+u];
            #pragma unroll
            for (int c=0;c<8;++c) {
                const float* wrow = W1 + c*DIMD + blk*32;
                #pragma unroll
                for (int u=0;u<8;++u)
                    acc[c] += tv[u].x*wrow[u*4+0]+tv[u].y*wrow[u*4+1]
                            + tv[u].z*wrow[u*4+2]+tv[u].w*wrow[u*4+3];
            }
        }
        int h=tid/14, w=tid-h*14;
        float* tp = TS + (h+1)*16 + (w+1);
        #pragma unroll
        for (int c=0;c<8;++c) tp[c*256]=acc[c];
    } else if (tid >= 208) {
        ((float4*)outb)[tid-208] = ((const float4*)xb)[tid-208];
    }
    __syncthreads();
    if (tid < 196) {
        int h=tid/14, w=tid-h*14;
        const float* tp = TS + (h+1)*16 + (w+1);
        float zv[8];
        #pragma unroll
        for (int c=0;c<8;++c) zv[c]=conv1_b[c];
        #pragma unroll
        for (int i=0;i<8;++i) {
            float t0=tp[i*256], tu=tp[i*256-16], td=tp[i*256+16], tl=tp[i*256-1], tr=tp[i*256+1];
            #pragma unroll
            for (int c=0;c<8;++c) {
                const float* wp = WB2 + (c*8+i)*8;
                float4 wv = *(const float4*)wp;
                zv[c] += wv.x*t0 + wv.y*tu + wv.z*tl + wv.w*tr + wp[4]*td;
            }
        }
        float* pp = PS + (h+1)*16 + (w+1);
        #pragma unroll
        for (int c=0;c<8;++c) {
            float mu=0.f, ga=0.f;
            #pragma unroll
            for (int i=0;i<8;++i) {
                const float* wp = WB2 + (c*8+i)*8;
                mu += wp[5]*zv[i]; ga += wp[6]*zv[i];
            }
            float e = ga*(zv[c]-mu);
            pp[c*256] = __expf(-e*e);
        }
    }
    __syncthreads();
    const int l  = tid & 63;
    const int wv = tid >> 6;
    const float4 ha0 = *(const float4*)(hist_w + l * 8);
    const float4 ha1 = *(const float4*)(hist_w + l * 8 + 4);
    const float4 hb0 = *(const float4*)(hist_w + (l + 64) * 8);
    const float4 hb1 = *(const float4*)(hist_w + (l + 64) * 8 + 4);
    const float4 hc0 = *(const float4*)(hist_w + (l + 128) * 8);
    const float4 hc1 = *(const float4*)(hist_w + (l + 128) * 8 + 4);
    const float  ba  = hist_b[l];
    const float  bb  = hist_b[l + 64];
    const float  bc  = hist_b[l + 128];
    if (tid < 196) {
        int h=tid/14, w=tid-h*14;
        const float* pb = PS + h*16 + w;
        #pragma unroll
        for (int c=0;c<8;++c) {
            const float* pr = pb + c*256;
            float s9 = pr[0]+pr[1]+pr[2]+pr[16]+pr[17]+pr[18]+pr[32]+pr[33]+pr[34];
            ZH[c*196+tid] = s9*(1.f/9.f);
        }
    }
    __syncthreads();
    {
        float* oy = outb + DIMD;
        const int n2beg = wv * 49;
        #pragma unroll 2
        for (int k = 0; k < 49; ++k) {
            const int n2 = n2beg + k;
            const float4 z0 = *(const float4*)(ZH + n2 * 8);
            const float4 z1 = *(const float4*)(ZH + n2 * 8 + 4);
            float a0 = ba + z0.x*ha0.x + z0.y*ha0.y + z0.z*ha0.z + z0.w*ha0.w
                          + z1.x*ha1.x + z1.y*ha1.y + z1.z*ha1.z + z1.w*ha1.w;
            float a1 = bb + z0.x*hb0.x + z0.y*hb0.y + z0.z*hb0.z + z0.w*hb0.w
                          + z1.x*hb1.x + z1.y*hb1.y + z1.z*hb1.z + z1.w*hb1.w;
            float a2 = bc + z0.x*hc0.x + z0.y*hc0.y + z0.z*hc0.z + z0.w*hc0.w
                          + z1.x*hc1.x + z1.y*hc1.y + z1.z*hc1.z + z1.w*hc1.w;
            float* orow = oy + n2 * DIMD;
            orow[l]       = a0;
            orow[l + 64]  = a1;
            orow[l + 128] = a2;
        }
    }
}

extern "C" void kernel_launch(void* const* d_in, const int* in_sizes, int n_in,
                              void* d_out, int out_size, void* d_ws, size_t ws_size,
                              hipStream_t stream)
{
    const float* x       = (const float*)d_in[0];
    const float* W1      = (const float*)d_in[1];
    const float* b1      = (const float*)d_in[2];
    const float* conv1_w = (const float*)d_in[3];
    const float* conv1_b = (const float*)d_in[4];
    const float* cdc_w   = (const float*)d_in[5];
    const float* wc1     = (const float*)d_in[6];
    const float* wc2     = (const float*)d_in[7];
    const float* hist_w  = (const float*)d_in[8];
    const float* hist_b  = (const float*)d_in[9];
    float* out = (float*)d_out;

    const size_t need = (size_t)2048 * 1568 * sizeof(float);   // 12.85 MB
    if (ws_size >= need) {
        float* zh_ws = (float*)d_ws;
        k1_head<<<2048, 256, 0, stream>>>(x, W1, b1, conv1_w, conv1_b, cdc_w,
                                          wc1, wc2, zh_ws, out);
        k2_hist<<<2048, 192, 0, stream>>>(zh_ws, hist_w, hist_b, out);
    } else {
        sadapter_fused<<<2048, 256, 0, stream>>>(
            x, W1, b1, conv1_w, conv1_b, cdc_w, wc1, wc2, hist_w, hist_b, out);
    }
}

// Round 12
// 166.959 us; speedup vs baseline: 1.0153x; 1.0153x over previous
//
#include <hip/hip_runtime.h>

// SAdapter v12: v11 with the nontemporal float4 fix (native ext_vector type).
// Fused 2-image pipelined kernel. Grid 1024; block handles images b and
// b+1024. Middle phase M2 interleaves D(image0) stores with A(image1) loads
// -> guaranteed HBM read/write overlap. LDS ping-pong:
//   r1: TS0 -> ZH0 -> P1 ; r2: P0 -> TS1 -> ZH1  (18432 B total)

#define DIMD 192
#define IMGS 37824           // 197*192
#define HB   1024            // half batch

typedef float vfloat4 __attribute__((ext_vector_type(4)));

__device__ __forceinline__ void phase_bc(const float* __restrict__ TSrc,
                                         float* __restrict__ Pdst,
                                         const float* __restrict__ WB2,
                                         const float* __restrict__ conv1_b,
                                         int tid)
{
    if (tid < 196) {
        int h = tid / 14, w = tid - h * 14;
        const float* tp = TSrc + (h + 1) * 16 + (w + 1);
        float zv[8];
        #pragma unroll
        for (int c = 0; c < 8; ++c) zv[c] = conv1_b[c];    // uniform -> s_load
        #pragma unroll
        for (int i = 0; i < 8; ++i) {
            float t0 = tp[i * 256];
            float tu = tp[i * 256 - 16];
            float td = tp[i * 256 + 16];
            float tl = tp[i * 256 - 1];
            float tr = tp[i * 256 + 1];
            #pragma unroll
            for (int c = 0; c < 8; ++c) {
                const float* wp = WB2 + (c * 8 + i) * 8;   // broadcast b128 + b32
                float4 wv = *(const float4*)wp;
                float wd = wp[4];
                zv[c] += wv.x * t0 + wv.y * tu + wv.z * tl + wv.w * tr + wd * td;
            }
        }
        float* pp = Pdst + (h + 1) * 16 + (w + 1);
        #pragma unroll
        for (int c = 0; c < 8; ++c) {
            float mu = 0.f, ga = 0.f;
            #pragma unroll
            for (int i = 0; i < 8; ++i) {
                const float* wp = WB2 + (c * 8 + i) * 8;
                mu += wp[5] * zv[i];
                ga += wp[6] * zv[i];
            }
            float e = ga * (zv[c] - mu);
            pp[c * 256] = __expf(-e * e);
        }
    }
}

__device__ __forceinline__ void phase_c2(const float* __restrict__ Psrc,
                                         float* __restrict__ ZHdst, int tid)
{
    if (tid < 196) {
        int h = tid / 14, w = tid - h * 14;
        const float* pb = Psrc + h * 16 + w;   // top-left of 3x3 (padded coords)
        #pragma unroll
        for (int c = 0; c < 8; ++c) {
            const float* pr = pb + c * 256;
            float s9 = pr[0]  + pr[1]  + pr[2]
                     + pr[16] + pr[17] + pr[18]
                     + pr[32] + pr[33] + pr[34];
            ZHdst[c * 196 + tid] = s9 * (1.f / 9.f);
        }
    }
}

__launch_bounds__(256)
__global__ void sadapter_pipe(
    const float* __restrict__ x,
    const float* __restrict__ W1,
    const float* __restrict__ b1,
    const float* __restrict__ conv1_w,
    const float* __restrict__ conv1_b,
    const float* __restrict__ cdc_w,
    const float* __restrict__ wc1,
    const float* __restrict__ wc2,
    const float* __restrict__ hist_w,
    const float* __restrict__ hist_b,
    float* __restrict__ out)
{
    __shared__ float smem[4608];   // 18432 B
    float* r1  = smem;             // TS0 -> ZH0 -> P1
    float* r2  = smem + 2048;      // P0  -> TS1 -> ZH1
    float* WB2 = smem + 4096;      // [64][8] packed small weights

    const int tid = threadIdx.x;
    const float* xb0 = x  + (size_t)blockIdx.x * IMGS;
    const float* xb1 = xb0 + (size_t)HB * IMGS;
    float* ob0 = out + (size_t)blockIdx.x * IMGS;
    float* ob1 = ob0 + (size_t)HB * IMGS;

    const float4 z4 = make_float4(0.f, 0.f, 0.f, 0.f);
    const float4 o4 = make_float4(1.f, 1.f, 1.f, 1.f);

    // ---- init: r1 zeros (TS0 borders), r2 ones (P0 borders), pack weights ----
    ((float4*)r1)[tid]       = z4;
    ((float4*)r1)[tid + 256] = z4;
    ((float4*)r2)[tid]       = o4;
    ((float4*)r2)[tid + 256] = o4;
    if (tid < 64) {
        const float* c5 = cdc_w + tid * 5;                 // cdc_w (8,8,1,5), tid=o*8+i
        float k0 = c5[0], k1 = c5[1], k2 = c5[2], k3 = c5[3], k4 = c5[4];
        float kd = k0 + k1 + k2 + k3 + k4;
        float* wp = WB2 + tid * 8;
        wp[0] = conv1_w[tid] + k2 - 0.7f * kd;  // center: 1x1 + cdc-center - theta*diff
        wp[1] = k0; wp[2] = k1; wp[3] = k3; wp[4] = k4;    // up,left,right,down
        wp[5] = wc1[tid];
        wp[6] = wc2[tid];
        wp[7] = 0.f;
    }
    __syncthreads();

    // ---- A0: t(i0) -> r1 ; idle threads: class-token copies for both images ----
    if (tid < 196) {
        const float4* rowp = (const float4*)(xb0 + DIMD + tid * DIMD);
        float acc0[8];
        #pragma unroll
        for (int c = 0; c < 8; ++c) acc0[c] = b1[c];       // uniform -> s_load
        #pragma unroll
        for (int blk = 0; blk < 6; ++blk) {
            float4 tv[8];
            #pragma unroll
            for (int u = 0; u < 8; ++u) tv[u] = rowp[blk * 8 + u];
            #pragma unroll
            for (int c = 0; c < 8; ++c) {
                const float* wrow = W1 + c * DIMD + blk * 32;
                #pragma unroll
                for (int u = 0; u < 8; ++u) {
                    acc0[c] += tv[u].x * wrow[u * 4 + 0] + tv[u].y * wrow[u * 4 + 1]
                             + tv[u].z * wrow[u * 4 + 2] + tv[u].w * wrow[u * 4 + 3];
                }
            }
        }
        int h = tid / 14, w = tid - h * 14;
        float* tp = r1 + (h + 1) * 16 + (w + 1);
        #pragma unroll
        for (int c = 0; c < 8; ++c) tp[c * 256] = acc0[c];
    } else {
        for (int f = tid - 196; f < 96; f += 60) {         // 2 x 48 float4 class rows
            int img = f / 48, j = f - img * 48;
            const vfloat4 v = ((const vfloat4*)(img ? xb1 : xb0))[j];
            __builtin_nontemporal_store(v, ((vfloat4*)(img ? ob1 : ob0)) + j);
        }
    }
    __syncthreads();

    // ---- BC0: r1 -> r2 (P0) ----
    phase_bc(r1, r2, WB2, conv1_b, tid);
    __syncthreads();

    // ---- C2_0: r2 -> r1[0:1568) (ZH0) ----
    phase_c2(r2, r1, tid);
    __syncthreads();

    // ---- M1: zero r2 (TS1 borders); load D weights (live through D1) ----
    ((float4*)r2)[tid]       = z4;
    ((float4*)r2)[tid + 256] = z4;
    const int l  = tid & 63;
    const int wv = tid >> 6;
    const float4 ha0 = *(const float4*)(hist_w + l * 8);
    const float4 ha1 = *(const float4*)(hist_w + l * 8 + 4);
    const float4 hb0 = *(const float4*)(hist_w + (l + 64) * 8);
    const float4 hb1 = *(const float4*)(hist_w + (l + 64) * 8 + 4);
    const float4 hc0 = *(const float4*)(hist_w + (l + 128) * 8);
    const float4 hc1 = *(const float4*)(hist_w + (l + 128) * 8 + 4);
    const float  ba  = hist_b[l];
    const float  bb  = hist_b[l + 64];
    const float  bc_ = hist_b[l + 128];
    const int n2beg = wv * 49;
    __syncthreads();

    // ---- M2: D0 (ZH0=r1 -> ob0 writes) interleaved with A1 (xb1 reads) ----
    float acc[8];
    #pragma unroll
    for (int c = 0; c < 8; ++c) acc[c] = b1[c];
    {
        const float4* rowp1 = (const float4*)(xb1 + DIMD + tid * DIMD);
        float* oy0 = ob0 + DIMD;
        for (int s = 0; s < 12; ++s) {
            if (tid < 196) {                               // A1: 16 dims per step
                float4 t0 = rowp1[s * 4 + 0];
                float4 t1 = rowp1[s * 4 + 1];
                float4 t2 = rowp1[s * 4 + 2];
                float4 t3 = rowp1[s * 4 + 3];
                #pragma unroll
                for (int c = 0; c < 8; ++c) {
                    const float* wr = W1 + c * DIMD + s * 16;  // uniform -> s_load
                    acc[c] += t0.x * wr[0]  + t0.y * wr[1]  + t0.z * wr[2]  + t0.w * wr[3]
                            + t1.x * wr[4]  + t1.y * wr[5]  + t1.z * wr[6]  + t1.w * wr[7]
                            + t2.x * wr[8]  + t2.y * wr[9]  + t2.z * wr[10] + t2.w * wr[11]
                            + t3.x * wr[12] + t3.y * wr[13] + t3.z * wr[14] + t3.w * wr[15];
                }
            }
            #pragma unroll
            for (int k = 0; k < 4; ++k) {                  // D0: 4 rows per step
                const int n2 = n2beg + s * 4 + k;
                const float4 z0 = *(const float4*)(r1 + n2 * 8);
                const float4 z1 = *(const float4*)(r1 + n2 * 8 + 4);
                float a0 = ba + z0.x*ha0.x + z0.y*ha0.y + z0.z*ha0.z + z0.w*ha0.w
                              + z1.x*ha1.x + z1.y*ha1.y + z1.z*ha1.z + z1.w*ha1.w;
                float a1 = bb + z0.x*hb0.x + z0.y*hb0.y + z0.z*hb0.z + z0.w*hb0.w
                              + z1.x*hb1.x + z1.y*hb1.y + z1.z*hb1.z + z1.w*hb1.w;
                float a2 = bc_+ z0.x*hc0.x + z0.y*hc0.y + z0.z*hc0.z + z0.w*hc0.w
                              + z1.x*hc1.x + z1.y*hc1.y + z1.z*hc1.z + z1.w*hc1.w;
                float* orow = oy0 + n2 * DIMD;
                __builtin_nontemporal_store(a0, orow + l);
                __builtin_nontemporal_store(a1, orow + l + 64);
                __builtin_nontemporal_store(a2, orow + l + 128);
            }
        }
        {                                                  // D0: leftover row 48
            const int n2 = n2beg + 48;
            const float4 z0 = *(const float4*)(r1 + n2 * 8);
            const float4 z1 = *(const float4*)(r1 + n2 * 8 + 4);
            float a0 = ba + z0.x*ha0.x + z0.y*ha0.y + z0.z*ha0.z + z0.w*ha0.w
                          + z1.x*ha1.x + z1.y*ha1.y + z1.z*ha1.z + z1.w*ha1.w;
            float a1 = bb + z0.x*hb0.x + z0.y*hb0.y + z0.z*hb0.z + z0.w*hb0.w
                          + z1.x*hb1.x + z1.y*hb1.y + z1.z*hb1.z + z1.w*hb1.w;
            float a2 = bc_+ z0.x*hc0.x + z0.y*hc0.y + z0.z*hc0.z + z0.w*hc0.w
                          + z1.x*hc1.x + z1.y*hc1.y + z1.z*hc1.z + z1.w*hc1.w;
            float* orow = oy0 + n2 * DIMD;
            __builtin_nontemporal_store(a0, orow + l);
            __builtin_nontemporal_store(a1, orow + l + 64);
            __builtin_nontemporal_store(a2, orow + l + 128);
        }
    }
    __syncthreads();

    // ---- N: ones-fill r1 (P1 borders); scatter acc -> TS1 (r2 interior) ----
    ((float4*)r1)[tid]       = o4;
    ((float4*)r1)[tid + 256] = o4;
    if (tid < 196) {
        int h = tid / 14, w = tid - h * 14;
        float* tp = r2 + (h + 1) * 16 + (w + 1);
        #pragma unroll
        for (int c = 0; c < 8; ++c) tp[c * 256] = acc[c];
    }
    __syncthreads();

    // ---- BC1: r2 -> r1 (P1) ----
    phase_bc(r2, r1, WB2, conv1_b, tid);
    __syncthreads();

    // ---- C2_1: r1 -> r2[0:1568) (ZH1) ----
    phase_c2(r1, r2, tid);
    __syncthreads();

    // ---- D1: ZH1 (r2) -> ob1 (weights still in regs) ----
    {
        float* oy1 = ob1 + DIMD;
        #pragma unroll 2
        for (int k = 0; k < 49; ++k) {
            const int n2 = n2beg + k;
            const float4 z0 = *(const float4*)(r2 + n2 * 8);
            const float4 z1 = *(const float4*)(r2 + n2 * 8 + 4);
            float a0 = ba + z0.x*ha0.x + z0.y*ha0.y + z0.z*ha0.z + z0.w*ha0.w
                          + z1.x*ha1.x + z1.y*ha1.y + z1.z*ha1.z + z1.w*ha1.w;
            float a1 = bb + z0.x*hb0.x + z0.y*hb0.y + z0.z*hb0.z + z0.w*hb0.w
                          + z1.x*hb1.x + z1.y*hb1.y + z1.z*hb1.z + z1.w*hb1.w;
            float a2 = bc_+ z0.x*hc0.x + z0.y*hc0.y + z0.z*hc0.z + z0.w*hc0.w
                          + z1.x*hc1.x + z1.y*hc1.y + z1.z*hc1.z + z1.w*hc1.w;
            float* orow = oy1 + n2 * DIMD;
            __builtin_nontemporal_store(a0, orow + l);
            __builtin_nontemporal_store(a1, orow + l + 64);
            __builtin_nontemporal_store(a2, orow + l + 128);
        }
    }
}

extern "C" void kernel_launch(void* const* d_in, const int* in_sizes, int n_in,
                              void* d_out, int out_size, void* d_ws, size_t ws_size,
                              hipStream_t stream)
{
    const float* x       = (const float*)d_in[0];
    const float* W1      = (const float*)d_in[1];
    const float* b1      = (const float*)d_in[2];
    const float* conv1_w = (const float*)d_in[3];
    const float* conv1_b = (const float*)d_in[4];
    const float* cdc_w   = (const float*)d_in[5];
    const float* wc1     = (const float*)d_in[6];
    const float* wc2     = (const float*)d_in[7];
    const float* hist_w  = (const float*)d_in[8];
    const float* hist_b  = (const float*)d_in[9];
    float* out = (float*)d_out;

    sadapter_pipe<<<1024, 256, 0, stream>>>(
        x, W1, b1, conv1_w, conv1_b, cdc_w, wc1, wc2, hist_w, hist_b, out);
}